// Round 1
// baseline (130.419 us; speedup 1.0000x reference)
//
#include <hip/hip_runtime.h>
#include <hip/hip_bf16.h>

#define NN 256
#define VC 32
#define FD 128
#define NH 8
#define NB 8
#define HIDN 64
#define NE (NN*(NN-1))   // 65280

typedef unsigned int uint32;
typedef unsigned short u16;

__device__ __forceinline__ float selu_f(float x) {
    // jax.nn.selu constants
    const float lam = 1.0507009873554805f;
    const float la  = 1.7580993408473766f;  // lam*alpha
    return x > 0.f ? lam * x : la * (__expf(x) - 1.f);
}

__device__ __forceinline__ u16 f32_to_bf16_rne(float f) {
    uint32 u = __float_as_uint(f);
    uint32 r = (u + 0x7fffu + ((u >> 16) & 1u)) >> 16;
    return (u16)r;
}

// ---------------------------------------------------------------- K1: node precompute
// A  = feat @ We1[0:128]            [256][64]
// Bf = feat @ We1[128:256] + be1    [256][64]
// FV = feat @ W_v                   [256][128]
// KQ[n][j][h] = sum_d Wk[j][16h+d] * (feat[n]@Wq)[16h+d] * 0.25   [256][64][8]
__global__ __launch_bounds__(256) void k1_pre(
    const float* __restrict__ feat, const float* __restrict__ We1,
    const float* __restrict__ be1, const float* __restrict__ Wq,
    const float* __restrict__ Wk, const float* __restrict__ Wv,
    float* __restrict__ A, float* __restrict__ Bf,
    float* __restrict__ FV, float* __restrict__ KQ)
{
    __shared__ float fl[FD];
    __shared__ float ql[FD];
    const int n = blockIdx.x;
    const int t = threadIdx.x;
    if (t < FD) fl[t] = feat[n*FD + t];
    __syncthreads();
    if (t < 64) {
        float a = 0.f;
        for (int i = 0; i < FD; ++i) a = fmaf(fl[i], We1[i*64 + t], a);
        A[n*64 + t] = a;
    } else if (t < 128) {
        const int j = t - 64;
        float a = be1[j];
        for (int i = 0; i < FD; ++i) a = fmaf(fl[i], We1[(FD+i)*64 + j], a);
        Bf[n*64 + j] = a;
    } else {
        const int j = t - 128;
        float a = 0.f;
        for (int i = 0; i < FD; ++i) a = fmaf(fl[i], Wq[i*FD + j], a);
        ql[j] = a * 0.25f;    // fold 1/sqrt(DH)
    }
    if (t < FD) {
        float a = 0.f;
        for (int i = 0; i < FD; ++i) a = fmaf(fl[i], Wv[i*FD + t], a);
        FV[n*FD + t] = a;
    }
    __syncthreads();
    for (int o = t; o < 512; o += 256) {
        const int j = o >> 3, h = o & 7;
        float a = 0.f;
        #pragma unroll
        for (int d = 0; d < 16; ++d)
            a = fmaf(Wk[j*FD + h*16 + d], ql[h*16 + d], a);
        KQ[n*512 + o] = a;
    }
}

// ---------------------------------------------------------------- K2: edge MLP
// per edge: radial[256] (Bessel * envelope), h = selu(A[s]+Bf[r]+radial@W1rad),
// h2 = selu(h@We2+be2)  -> stored bf16 [E][64]
#define K2_TILES 4
__global__ __launch_bounds__(256, 2) void k2_edge(
    const float* __restrict__ pos, const float* __restrict__ We1,
    const float* __restrict__ We2, const float* __restrict__ be2,
    const float* __restrict__ A, const float* __restrict__ Bf,
    u16* __restrict__ h2g)
{
    __shared__ u16   w1[256*64];   // bf16 radial part of We1  (32 KB)
    __shared__ float radt[256*32]; // [i][edge]                (32 KB)
    __shared__ float ht[64*36];    // [i][edge(32)+pad]        (9 KB)
    const int t = threadIdx.x;
    const int wave = t >> 6, lane = t & 63;

    for (int o = t; o < 256*64; o += 256)
        w1[o] = f32_to_bf16_rne(We1[256*64 + o]);
    __syncthreads();

    const int tile0 = blockIdx.x * K2_TILES;
    for (int it = 0; it < K2_TILES; ++it) {
        const int e0 = (tile0 + it) * 32;
        __syncthreads();    // previous tile's radt readers done
        // ---- phase A: radial features for 32 edges x 32 channels
        for (int p = t; p < 1024; p += 256) {
            const int ei = p & 31, v = p >> 5;
            const uint32 e = (uint32)(e0 + ei);
            const uint32 s = e / 255u;
            const uint32 rr = e - s*255u;
            const uint32 r = rr + (rr >= s ? 1u : 0u);
            const float* ps = pos + (s*VC + v)*3;
            const float* pr = pos + (r*VC + v)*3;
            const float dx = ps[0]-pr[0], dy = ps[1]-pr[1], dz = ps[2]-pr[2];
            const float d2 = fmaf(dx,dx,fmaf(dy,dy,dz*dz)) + 1e-18f;
            const float len = sqrtf(d2);
            const float x = fmaxf(len, 1e-6f);
            const float tt = 2.f - 0.4f*len;
            const float env = tt > 0.f ? 1.9784655248401538f * __expf(-1.f/tt) : 0.f;
            const float coefc = 0.6324555320336759f * env / x;  // sqrt(2/5)*env/x
            float s_cur, c1;
            __sincosf(0.6283185307179586f * x, &s_cur, &c1);    // pi*x/5
            const float c2 = 2.f * c1;
            float s_prev = 0.f;
            float* col = radt + v*256 + ei;
            #pragma unroll
            for (int b = 0; b < 8; ++b) {                        // sin((b+1)theta) recurrence
                col[b*32] = coefc * s_cur;
                const float s_next = fmaf(c2, s_cur, -s_prev);
                s_prev = s_cur; s_cur = s_next;
            }
        }
        __syncthreads();    // radt ready
        // ---- GEMM1: each wave owns 8 edges, each lane one hidden col
        const uint32 ebase = (uint32)(e0 + wave*8);
        float acc[8];
        #pragma unroll
        for (int k = 0; k < 8; ++k) {
            const uint32 e = ebase + k;
            const uint32 s = e / 255u;
            const uint32 rr = e - s*255u;
            const uint32 r = rr + (rr >= s ? 1u : 0u);
            acc[k] = A[s*64 + lane] + Bf[r*64 + lane];
        }
        #pragma unroll 4
        for (int i = 0; i < 256; ++i) {
            const float wv = __uint_as_float(((uint32)w1[i*64 + lane]) << 16);
            const float4 r0 = *(const float4*)(radt + i*32 + wave*8);
            const float4 r1 = *(const float4*)(radt + i*32 + wave*8 + 4);
            acc[0] = fmaf(wv, r0.x, acc[0]);
            acc[1] = fmaf(wv, r0.y, acc[1]);
            acc[2] = fmaf(wv, r0.z, acc[2]);
            acc[3] = fmaf(wv, r0.w, acc[3]);
            acc[4] = fmaf(wv, r1.x, acc[4]);
            acc[5] = fmaf(wv, r1.y, acc[5]);
            acc[6] = fmaf(wv, r1.z, acc[6]);
            acc[7] = fmaf(wv, r1.w, acc[7]);
        }
        #pragma unroll
        for (int k = 0; k < 8; ++k)
            ht[lane*36 + wave*8 + k] = selu_f(acc[k]);
        __syncthreads();    // ht transpose visible
        // ---- GEMM2
        float acc2[8];
        const float b2 = be2[lane];
        #pragma unroll
        for (int k = 0; k < 8; ++k) acc2[k] = b2;
        #pragma unroll 4
        for (int i = 0; i < 64; ++i) {
            const float wv = We2[i*64 + lane];
            const float4 h0 = *(const float4*)(ht + i*36 + wave*8);
            const float4 h1 = *(const float4*)(ht + i*36 + wave*8 + 4);
            acc2[0] = fmaf(wv, h0.x, acc2[0]);
            acc2[1] = fmaf(wv, h0.y, acc2[1]);
            acc2[2] = fmaf(wv, h0.z, acc2[2]);
            acc2[3] = fmaf(wv, h0.w, acc2[3]);
            acc2[4] = fmaf(wv, h1.x, acc2[4]);
            acc2[5] = fmaf(wv, h1.y, acc2[5]);
            acc2[6] = fmaf(wv, h1.z, acc2[6]);
            acc2[7] = fmaf(wv, h1.w, acc2[7]);
        }
        #pragma unroll
        for (int k = 0; k < 8; ++k) {
            const uint32 e = ebase + k;
            h2g[(size_t)e*64 + lane] = f32_to_bf16_rne(selu_f(acc2[k]));
        }
    }
}

// ---------------------------------------------------------------- K3: per-receiver
__global__ __launch_bounds__(256) void k3_recv(
    const float* __restrict__ pos, const float* __restrict__ feat,
    const u16* __restrict__ h2g,
    const float* __restrict__ KQ, const float* __restrict__ Wvec,
    const float* __restrict__ FV, const float* __restrict__ Wmix,
    const float* __restrict__ M1, const float* __restrict__ bm1,
    const float* __restrict__ M2, const float* __restrict__ bm2,
    const float* __restrict__ M3, const float* __restrict__ bm3,
    float* __restrict__ out0, float* __restrict__ out1)
{
    __shared__ float kq[512];       // [j][h]
    __shared__ float wvl[2048];     // [j][v]
    __shared__ float al[256*9];     // logits -> alpha (pad 9)
    __shared__ float cf[256*33];    // coeff -> wmsg  (pad 33)
    __shared__ float posr[96];
    __shared__ float invp[256];
    __shared__ float inva[128];
    __shared__ float vecl[96];
    __shared__ float hi1[64];
    __shared__ float hi2[64];
    const int r = blockIdx.x;
    const int t = threadIdx.x;
    for (int o = t; o < 512; o += 256) kq[o] = KQ[r*512 + o];
    for (int o = t; o < 2048; o += 256) wvl[o] = Wvec[o];
    if (t < 96) posr[t] = pos[r*96 + t];
    __syncthreads();
    // ---- P1: per sender: logit[8] and coeff[32] from h2 row
    {
        const int s = t;
        if (s == r) {
            #pragma unroll
            for (int h = 0; h < 8; ++h) al[s*9 + h] = -1e30f;
            #pragma unroll
            for (int v = 0; v < 32; ++v) cf[s*33 + v] = 0.f;
        } else {
            const uint32 e = (uint32)s*255u + (uint32)r - (r > s ? 1u : 0u);
            const uint4* hrow = (const uint4*)(h2g + (size_t)e*64);
            float lg[8], cv[32];
            #pragma unroll
            for (int h = 0; h < 8; ++h) lg[h] = 0.f;
            #pragma unroll
            for (int v = 0; v < 32; ++v) cv[v] = 0.f;
            #pragma unroll
            for (int c4 = 0; c4 < 8; ++c4) {
                const uint4 u = hrow[c4];
                float hv[8];
                hv[0] = __uint_as_float(u.x << 16);
                hv[1] = __uint_as_float(u.x & 0xffff0000u);
                hv[2] = __uint_as_float(u.y << 16);
                hv[3] = __uint_as_float(u.y & 0xffff0000u);
                hv[4] = __uint_as_float(u.z << 16);
                hv[5] = __uint_as_float(u.z & 0xffff0000u);
                hv[6] = __uint_as_float(u.w << 16);
                hv[7] = __uint_as_float(u.w & 0xffff0000u);
                #pragma unroll
                for (int m = 0; m < 8; ++m) {
                    const int j = c4*8 + m;
                    const float hj = hv[m];
                    #pragma unroll
                    for (int h = 0; h < 8; ++h) lg[h] = fmaf(hj, kq[j*8+h], lg[h]);
                    #pragma unroll
                    for (int v = 0; v < 32; ++v) cv[v] = fmaf(hj, wvl[j*32+v], cv[v]);
                }
            }
            #pragma unroll
            for (int h = 0; h < 8; ++h) al[s*9+h] = lg[h];
            #pragma unroll
            for (int v = 0; v < 32; ++v) cf[s*33+v] = cv[v];
        }
    }
    __syncthreads();
    // ---- P2: segment softmax per head (exact max + denom)
    {
        const int h = t >> 5, u = t & 31;
        float lgv[8];
        #pragma unroll
        for (int k = 0; k < 8; ++k) lgv[k] = al[(u + 32*k)*9 + h];
        float m = lgv[0];
        #pragma unroll
        for (int k = 1; k < 8; ++k) m = fmaxf(m, lgv[k]);
        m = fmaxf(m, __shfl_xor(m, 16));
        m = fmaxf(m, __shfl_xor(m, 8));
        m = fmaxf(m, __shfl_xor(m, 4));
        m = fmaxf(m, __shfl_xor(m, 2));
        m = fmaxf(m, __shfl_xor(m, 1));
        float ex[8]; float ds = 0.f;
        #pragma unroll
        for (int k = 0; k < 8; ++k) { ex[k] = __expf(lgv[k] - m); ds += ex[k]; }
        ds += __shfl_xor(ds, 16);
        ds += __shfl_xor(ds, 8);
        ds += __shfl_xor(ds, 4);
        ds += __shfl_xor(ds, 2);
        ds += __shfl_xor(ds, 1);
        const float inv_d = 1.f / (ds + 1e-12f);
        #pragma unroll
        for (int k = 0; k < 8; ++k) al[(u + 32*k)*9 + h] = ex[k] * inv_d;
    }
    __syncthreads();
    // ---- P3: wmsg[s][v] = alpha[s][v/4]*coeff*sqrt(3)*invlen
    for (int p = t; p < 8192; p += 256) {
        const int s = p >> 5, v = p & 31;
        const float* ps = pos + (s*VC + v)*3;
        const float dx = ps[0]-posr[v*3], dy = ps[1]-posr[v*3+1], dz = ps[2]-posr[v*3+2];
        const float d2 = fmaf(dx,dx,fmaf(dy,dy,dz*dz)) + 1e-18f;
        cf[s*33+v] = al[s*9 + (v>>2)] * cf[s*33+v] * 1.7320508075688772f * rsqrtf(d2);
    }
    __syncthreads();
    // ---- P4a: inv_agg (two halves), P4b: vec_agg
    {
        const int f = t & 127, half = t >> 7;
        const int h = f >> 4;
        float a = 0.f;
        for (int s = half*128; s < half*128 + 128; ++s)
            a = fmaf(al[s*9 + h], FV[s*FD + f], a);
        invp[t] = a;
    }
    if (t < 96) {
        const int v = t / 3, c = t - (t/3)*3;
        float a = 0.f;
        for (int s = 0; s < 256; ++s)
            a = fmaf(cf[s*33+v], pos[(s*VC+v)*3 + c] - posr[t], a);
        vecl[t] = a;
    }
    __syncthreads();
    if (t < 128) inva[t] = invp[t] + invp[128 + t];
    __syncthreads();
    if (t < 64) {
        float a = bm1[t];
        for (int i = 0; i < 128; ++i) a = fmaf(inva[i], M1[i*64 + t], a);
        hi1[t] = selu_f(a);
    }
    __syncthreads();
    if (t < 64) {
        float a = bm2[t];
        #pragma unroll 8
        for (int i = 0; i < 64; ++i) a = fmaf(hi1[i], M2[i*64 + t], a);
        hi2[t] = selu_f(a);
    }
    __syncthreads();
    if (t < 128) {
        float a = bm3[t];
        #pragma unroll 8
        for (int i = 0; i < 64; ++i) a = fmaf(hi2[i], M3[i*FD + t], a);
        out1[r*FD + t] = a + feat[r*FD + t];
    } else if (t < 224) {
        const int o = t - 128;
        const int w = o / 3, c = o - (o/3)*3;
        float a = 0.f;
        #pragma unroll
        for (int v = 0; v < 32; ++v)
            a = fmaf(vecl[v*3 + c], Wmix[v*32 + w], a);
        out0[r*96 + o] = a + pos[r*96 + o];
    }
}

extern "C" void kernel_launch(void* const* d_in, const int* in_sizes, int n_in,
                              void* d_out, int out_size, void* d_ws, size_t ws_size,
                              hipStream_t stream)
{
    const float* pos  = (const float*)d_in[0];
    const float* feat = (const float*)d_in[1];
    const float* We1  = (const float*)d_in[2];
    const float* be1  = (const float*)d_in[3];
    const float* We2  = (const float*)d_in[4];
    const float* be2  = (const float*)d_in[5];
    const float* Wq   = (const float*)d_in[6];
    const float* Wk   = (const float*)d_in[7];
    const float* Wv   = (const float*)d_in[8];
    const float* Wvec = (const float*)d_in[9];
    const float* Wmix = (const float*)d_in[10];
    const float* M1   = (const float*)d_in[11];
    const float* bm1  = (const float*)d_in[12];
    const float* M2   = (const float*)d_in[13];
    const float* bm2  = (const float*)d_in[14];
    const float* M3   = (const float*)d_in[15];
    const float* bm3  = (const float*)d_in[16];

    float* ws = (float*)d_ws;
    float* A   = ws;                 // [256][64]
    float* Bf  = ws + 16384;         // [256][64]
    float* FV  = ws + 32768;         // [256][128]
    float* KQ  = ws + 65536;         // [256][512]
    u16*   h2  = (u16*)(ws + 196608);// [E][64] bf16
    if (ws_size < (size_t)196608*4 + (size_t)NE*64*2) return;

    float* out0 = (float*)d_out;          // [256][32][3]
    float* out1 = out0 + NN*VC*3;         // [256][128]

    hipLaunchKernelGGL(k1_pre, dim3(256), dim3(256), 0, stream,
                       feat, We1, be1, Wq, Wk, Wv, A, Bf, FV, KQ);
    hipLaunchKernelGGL(k2_edge, dim3(510), dim3(256), 0, stream,
                       pos, We1, We2, be2, A, Bf, h2);
    hipLaunchKernelGGL(k3_recv, dim3(256), dim3(256), 0, stream,
                       pos, feat, h2, KQ, Wvec, FV, Wmix,
                       M1, bm1, M2, bm2, M3, bm3, out0, out1);
}

// Round 2
// 107.459 us; speedup vs baseline: 1.2137x; 1.2137x over previous
//
#include <hip/hip_runtime.h>
#include <hip/hip_bf16.h>

#define NN 256
#define VC 32
#define FD 128

typedef unsigned int uint32;
typedef unsigned short u16;
typedef __attribute__((ext_vector_type(8))) short bf16x8;
typedef __attribute__((ext_vector_type(4))) float f32x4;

__device__ __forceinline__ float selu_f(float x) {
    const float lam = 1.0507009873554805f;
    const float la  = 1.7580993408473766f;
    return x > 0.f ? lam * x : la * (__expf(x) - 1.f);
}

__device__ __forceinline__ u16 f32_to_bf16_rne(float f) {
    uint32 u = __float_as_uint(f);
    uint32 r = (u + 0x7fffu + ((u >> 16) & 1u)) >> 16;
    return (u16)r;
}

__device__ __forceinline__ float bf16_to_f32(u16 h) {
    return __uint_as_float(((uint32)h) << 16);
}

// ---------------------------------------------------------------- K1: node precompute
// A  = feat @ We1[0:128]            [256][64]
// Bf = feat @ We1[128:256] + be1    [256][64]
// FV = feat @ W_v                   [256][128]
// KQ[n][j][h] = sum_d Wk[j][16h+d] * (feat[n]@Wq)[16h+d] * 0.25   [256][j*8+h]
__global__ __launch_bounds__(256) void k1_pre(
    const float* __restrict__ feat, const float* __restrict__ We1,
    const float* __restrict__ be1, const float* __restrict__ Wq,
    const float* __restrict__ Wk, const float* __restrict__ Wv,
    float* __restrict__ A, float* __restrict__ Bf,
    float* __restrict__ FV, float* __restrict__ KQ)
{
    __shared__ float fl[FD];
    __shared__ float ql[FD];
    const int n = blockIdx.x;
    const int t = threadIdx.x;
    if (t < FD) fl[t] = feat[n*FD + t];
    __syncthreads();
    if (t < 64) {
        float a = 0.f;
        for (int i = 0; i < FD; ++i) a = fmaf(fl[i], We1[i*64 + t], a);
        A[n*64 + t] = a;
    } else if (t < 128) {
        const int j = t - 64;
        float a = be1[j];
        for (int i = 0; i < FD; ++i) a = fmaf(fl[i], We1[(FD+i)*64 + j], a);
        Bf[n*64 + j] = a;
    } else {
        const int j = t - 128;
        float a = 0.f;
        for (int i = 0; i < FD; ++i) a = fmaf(fl[i], Wq[i*FD + j], a);
        ql[j] = a * 0.25f;
    }
    if (t < FD) {
        float a = 0.f;
        for (int i = 0; i < FD; ++i) a = fmaf(fl[i], Wv[i*FD + t], a);
        FV[n*FD + t] = a;
    }
    __syncthreads();
    for (int o = t; o < 512; o += 256) {
        const int j = o >> 3, h = o & 7;
        float a = 0.f;
        #pragma unroll
        for (int d = 0; d < 16; ++d)
            a = fmaf(Wk[j*FD + h*16 + d], ql[h*16 + d], a);
        KQ[n*512 + o] = a;
    }
}

// ---------------------------------------------------------------- K2: edge pipeline (MFMA)
// Receiver-major edges: block b -> r = b>>1, 4 tiles of 32 senders (s' = tt*32+e).
// Per tile: radial built directly in B-frag registers; GEMM1(K=256) -> selu ->
// GEMM2(K=64) -> selu -> {GEMM3 coeff (K=64), logit MFMA (K=64)}.
// Outputs: lgg[r][s'][8] f32, cfg[r][s'][32] bf16 (coeff * sqrt3 / len).
__global__ __launch_bounds__(256) void k2_edge(
    const float* __restrict__ pos, const float* __restrict__ We1,
    const float* __restrict__ We2, const float* __restrict__ be2,
    const float* __restrict__ Ag, const float* __restrict__ Bfg,
    const float* __restrict__ KQ, const float* __restrict__ Wvec,
    float* __restrict__ lgg, u16* __restrict__ cfg)
{
    __shared__ u16 h1b[32*64];      // [e][c] bf16, xor-swizzled
    __shared__ u16 h2b[32*64];
    __shared__ float invl[32*33];   // [e][v] padded
    __shared__ u16 cfs[32*32];      // staging for coalesced cf writes

    const int t = threadIdx.x;
    const int wave = t >> 6, l = t & 63;
    const int li = l & 15, q = l >> 4;
    const int mh = wave >> 1, eh = wave & 1;
    const int r = blockIdx.x >> 1, tpart = blockIdx.x & 1;
    const int e = eh*16 + li;       // edge row within tile
    const int swz = (e & 7) << 3;   // u16-index xor for 16B-granular spread

    // ---- per-block register A-fragments (weights)
    bf16x8 w1A[2][8];               // GEMM1: rows c = mh*32+mt*16+li, k over 256
    #pragma unroll
    for (int mt = 0; mt < 2; ++mt) {
        const int c = mh*32 + mt*16 + li;
        #pragma unroll
        for (int kb = 0; kb < 8; ++kb)
            #pragma unroll
            for (int j = 0; j < 8; ++j)
                w1A[mt][kb][j] = (short)f32_to_bf16_rne(We1[(256 + kb*32 + q*8 + j)*64 + c]);
    }
    bf16x8 we2A[2][2];              // GEMM2: rows c2, k = c over 64
    #pragma unroll
    for (int mt = 0; mt < 2; ++mt) {
        const int c2 = mh*32 + mt*16 + li;
        #pragma unroll
        for (int kb = 0; kb < 2; ++kb)
            #pragma unroll
            for (int j = 0; j < 8; ++j)
                we2A[mt][kb][j] = (short)f32_to_bf16_rne(We2[(kb*32 + q*8 + j)*64 + c2]);
    }
    bf16x8 wvA[2];                  // GEMM3: rows v = mh*16+li, k = c2 over 64
    {
        const int v = mh*16 + li;
        #pragma unroll
        for (int kb = 0; kb < 2; ++kb)
            #pragma unroll
            for (int j = 0; j < 8; ++j)
                wvA[kb][j] = (short)f32_to_bf16_rne(Wvec[(kb*32 + q*8 + j)*32 + v]);
    }
    bf16x8 kqA[2];                  // logit: rows h'=li (<8), k = c2 over 64
    #pragma unroll
    for (int kb = 0; kb < 2; ++kb)
        #pragma unroll
        for (int j = 0; j < 8; ++j)
            kqA[kb][j] = (li < 8) ? (short)f32_to_bf16_rne(KQ[r*512 + (kb*32 + q*8 + j)*8 + li]) : (short)0;

    float bfreg[2][4], be2reg[2][4];
    #pragma unroll
    for (int mt = 0; mt < 2; ++mt)
        #pragma unroll
        for (int rg = 0; rg < 4; ++rg) {
            const int c = mh*32 + mt*16 + q*4 + rg;
            bfreg[mt][rg] = Bfg[r*64 + c];
            be2reg[mt][rg] = be2[c];
        }

    for (int it = 0; it < 4; ++it) {
        const int tt = tpart*4 + it;
        const int s0 = tt*32;
        const int sp = s0 + e;
        int s = sp + (sp >= r ? 1 : 0); if (s > 255) s = 255;
        __syncthreads();    // protect h1b/invl/cfs reuse from previous tile

        // ---- P0: radial basis directly into B-fragments (one (e,v) per lane per frag)
        bf16x8 radF[8];
        #pragma unroll
        for (int kb = 0; kb < 8; ++kb) {
            const int v = kb*4 + q;
            const float* ps = pos + (s*VC + v)*3;
            const float* pr = pos + (r*VC + v)*3;
            const float dx = ps[0]-pr[0], dy = ps[1]-pr[1], dz = ps[2]-pr[2];
            const float d2 = fmaf(dx,dx,fmaf(dy,dy,dz*dz)) + 1e-18f;
            const float len = sqrtf(d2);
            invl[e*33 + v] = rsqrtf(d2);
            const float x = fmaxf(len, 1e-6f);
            const float tt2 = 2.f - 0.4f*len;
            const float env = tt2 > 0.f ? 1.9784655248401538f * __expf(-1.f/tt2) : 0.f;
            const float coefc = 0.6324555320336759f * env / x;
            float s_cur, c1;
            __sincosf(0.6283185307179586f * x, &s_cur, &c1);
            const float c2x = 2.f * c1;
            float s_prev = 0.f;
            #pragma unroll
            for (int b = 0; b < 8; ++b) {
                radF[kb][b] = (short)f32_to_bf16_rne(coefc * s_cur);
                const float s_next = fmaf(c2x, s_cur, -s_prev);
                s_prev = s_cur; s_cur = s_next;
            }
        }
        // per-edge bias rows A[s][c]
        float As[2][4];
        #pragma unroll
        for (int mt = 0; mt < 2; ++mt)
            #pragma unroll
            for (int rg = 0; rg < 4; ++rg)
                As[mt][rg] = Ag[s*64 + mh*32 + mt*16 + q*4 + rg];

        // ---- GEMM1: h1[c][e] = radial @ We1_rad
        f32x4 d1[2] = {{0.f,0.f,0.f,0.f},{0.f,0.f,0.f,0.f}};
        #pragma unroll
        for (int kb = 0; kb < 8; ++kb) {
            d1[0] = __builtin_amdgcn_mfma_f32_16x16x32_bf16(w1A[0][kb], radF[kb], d1[0], 0, 0, 0);
            d1[1] = __builtin_amdgcn_mfma_f32_16x16x32_bf16(w1A[1][kb], radF[kb], d1[1], 0, 0, 0);
        }
        #pragma unroll
        for (int mt = 0; mt < 2; ++mt) {
            const int c0 = mh*32 + mt*16 + q*4;
            const u16 p0 = f32_to_bf16_rne(selu_f(d1[mt][0] + As[mt][0] + bfreg[mt][0]));
            const u16 p1 = f32_to_bf16_rne(selu_f(d1[mt][1] + As[mt][1] + bfreg[mt][1]));
            const u16 p2 = f32_to_bf16_rne(selu_f(d1[mt][2] + As[mt][2] + bfreg[mt][2]));
            const u16 p3 = f32_to_bf16_rne(selu_f(d1[mt][3] + As[mt][3] + bfreg[mt][3]));
            *(uint32*)&h1b[e*64 + ((c0)     ^ swz)] = (uint32)p0 | ((uint32)p1 << 16);
            *(uint32*)&h1b[e*64 + ((c0 + 2) ^ swz)] = (uint32)p2 | ((uint32)p3 << 16);
        }
        __syncthreads();    // h1 ready

        // ---- GEMM2: h2 = selu(h1 @ We2 + be2)
        f32x4 d2[2] = {{0.f,0.f,0.f,0.f},{0.f,0.f,0.f,0.f}};
        #pragma unroll
        for (int kb = 0; kb < 2; ++kb) {
            const bf16x8 hb = *(const bf16x8*)&h1b[e*64 + ((kb*32 + q*8) ^ swz)];
            d2[0] = __builtin_amdgcn_mfma_f32_16x16x32_bf16(we2A[0][kb], hb, d2[0], 0, 0, 0);
            d2[1] = __builtin_amdgcn_mfma_f32_16x16x32_bf16(we2A[1][kb], hb, d2[1], 0, 0, 0);
        }
        #pragma unroll
        for (int mt = 0; mt < 2; ++mt) {
            const int c0 = mh*32 + mt*16 + q*4;
            const u16 p0 = f32_to_bf16_rne(selu_f(d2[mt][0] + be2reg[mt][0]));
            const u16 p1 = f32_to_bf16_rne(selu_f(d2[mt][1] + be2reg[mt][1]));
            const u16 p2 = f32_to_bf16_rne(selu_f(d2[mt][2] + be2reg[mt][2]));
            const u16 p3 = f32_to_bf16_rne(selu_f(d2[mt][3] + be2reg[mt][3]));
            *(uint32*)&h2b[e*64 + ((c0)     ^ swz)] = (uint32)p0 | ((uint32)p1 << 16);
            *(uint32*)&h2b[e*64 + ((c0 + 2) ^ swz)] = (uint32)p2 | ((uint32)p3 << 16);
        }
        __syncthreads();    // h2 ready

        // ---- GEMM3 (coeff) + logit MFMA, sharing the h2 B-fragments
        f32x4 d3 = {0.f,0.f,0.f,0.f};
        f32x4 dl = {0.f,0.f,0.f,0.f};
        #pragma unroll
        for (int kb = 0; kb < 2; ++kb) {
            const bf16x8 hb = *(const bf16x8*)&h2b[e*64 + ((kb*32 + q*8) ^ swz)];
            d3 = __builtin_amdgcn_mfma_f32_16x16x32_bf16(wvA[kb], hb, d3, 0, 0, 0);
            if (mh == 0)
                dl = __builtin_amdgcn_mfma_f32_16x16x32_bf16(kqA[kb], hb, dl, 0, 0, 0);
        }
        {   // cf = coeff * sqrt(3) / len  -> staged bf16
            const int v0 = mh*16 + q*4;
            const u16 p0 = f32_to_bf16_rne(d3[0] * 1.7320508075688772f * invl[e*33 + v0]);
            const u16 p1 = f32_to_bf16_rne(d3[1] * 1.7320508075688772f * invl[e*33 + v0+1]);
            const u16 p2 = f32_to_bf16_rne(d3[2] * 1.7320508075688772f * invl[e*33 + v0+2]);
            const u16 p3 = f32_to_bf16_rne(d3[3] * 1.7320508075688772f * invl[e*33 + v0+3]);
            *(uint32*)&cfs[e*32 + v0]     = (uint32)p0 | ((uint32)p1 << 16);
            *(uint32*)&cfs[e*32 + v0 + 2] = (uint32)p2 | ((uint32)p3 << 16);
        }
        if (mh == 0 && q < 2) {
            float4 st = make_float4(dl[0], dl[1], dl[2], dl[3]);
            *(float4*)&lgg[((size_t)r*256 + sp)*8 + q*4] = st;
        }
        __syncthreads();    // cfs ready
        {
            uint32* dst = (uint32*)(cfg + ((size_t)r*256 + s0)*32);
            const uint32* src = (const uint32*)cfs;
            for (int p = t; p < 512; p += 256) dst[p] = src[p];
        }
    }
}

// ---------------------------------------------------------------- K3: per-receiver
__global__ __launch_bounds__(256) void k3_recv(
    const float* __restrict__ pos, const float* __restrict__ feat,
    const float* __restrict__ lgg, const u16* __restrict__ cfg,
    const float* __restrict__ FV, const float* __restrict__ Wmix,
    const float* __restrict__ M1, const float* __restrict__ bm1,
    const float* __restrict__ M2, const float* __restrict__ bm2,
    const float* __restrict__ M3, const float* __restrict__ bm3,
    float* __restrict__ out0, float* __restrict__ out1)
{
    __shared__ float alpha[256*9];   // [s'][h]
    __shared__ float wm[256*33];     // [s'][v]
    __shared__ float invp[256];
    __shared__ float vpa[192], vpb[192];
    __shared__ float inva[128], vecl[96], hi1[64], hi2[64];
    const int r = blockIdx.x;
    const int t = threadIdx.x;

    // ---- softmax over 255 senders per head
    {
        const int h = t >> 5, u = t & 31;
        float lgv[8];
        #pragma unroll
        for (int k = 0; k < 8; ++k) {
            const int sp = u + 32*k;
            lgv[k] = (sp < 255) ? lgg[((size_t)r*256 + sp)*8 + h] : -1e30f;
        }
        float m = lgv[0];
        #pragma unroll
        for (int k = 1; k < 8; ++k) m = fmaxf(m, lgv[k]);
        m = fmaxf(m, __shfl_xor(m, 16));
        m = fmaxf(m, __shfl_xor(m, 8));
        m = fmaxf(m, __shfl_xor(m, 4));
        m = fmaxf(m, __shfl_xor(m, 2));
        m = fmaxf(m, __shfl_xor(m, 1));
        float ex[8]; float ds = 0.f;
        #pragma unroll
        for (int k = 0; k < 8; ++k) { ex[k] = __expf(lgv[k] - m); ds += ex[k]; }
        ds += __shfl_xor(ds, 16);
        ds += __shfl_xor(ds, 8);
        ds += __shfl_xor(ds, 4);
        ds += __shfl_xor(ds, 2);
        ds += __shfl_xor(ds, 1);
        const float inv_d = 1.f / (ds + 1e-12f);
        #pragma unroll
        for (int k = 0; k < 8; ++k) alpha[(u + 32*k)*9 + h] = ex[k] * inv_d;
    }
    __syncthreads();
    // ---- wm[s'][v] = alpha[s'][v/4] * cf   (cf already has sqrt3/len)
    for (int p = t; p < 8192; p += 256) {
        const int sp = p >> 5, v = p & 31;
        wm[sp*33 + v] = alpha[sp*9 + (v>>2)] * bf16_to_f32(cfg[((size_t)r*256 + sp)*32 + v]);
    }
    __syncthreads();
    // ---- inv_agg partials + vec_agg partials
    {
        const int f = t & 127, half = t >> 7;
        const int h = f >> 4;
        const int sA = half*128, sB = half ? 255 : 128;
        float a = 0.f;
        for (int sp = sA; sp < sB; ++sp) {
            const int s = sp + (sp >= r ? 1 : 0);
            a = fmaf(alpha[sp*9 + h], FV[s*FD + f], a);
        }
        invp[t] = a;
    }
    if (t < 192) {
        const int o = t >> 1, half = t & 1;
        const int v = o / 3, c = o - 3*(o/3);
        const int sA = half*128, sB = half ? 255 : 128;
        float a = 0.f, b = 0.f;
        for (int sp = sA; sp < sB; ++sp) {
            const float w = wm[sp*33 + v];
            const int s = sp + (sp >= r ? 1 : 0);
            a = fmaf(w, pos[(s*VC + v)*3 + c], a);
            b += w;
        }
        vpa[t] = a; vpb[t] = b;
    }
    __syncthreads();
    if (t < 128) inva[t] = invp[t] + invp[128 + t];
    if (t < 96) vecl[t] = (vpa[2*t] + vpa[2*t+1]) - (vpb[2*t] + vpb[2*t+1]) * pos[r*96 + t];
    __syncthreads();
    if (t < 64) {
        float a = bm1[t];
        for (int i = 0; i < 128; ++i) a = fmaf(inva[i], M1[i*64 + t], a);
        hi1[t] = selu_f(a);
    }
    __syncthreads();
    if (t < 64) {
        float a = bm2[t];
        #pragma unroll 8
        for (int i = 0; i < 64; ++i) a = fmaf(hi1[i], M2[i*64 + t], a);
        hi2[t] = selu_f(a);
    }
    __syncthreads();
    if (t < 128) {
        float a = bm3[t];
        #pragma unroll 8
        for (int i = 0; i < 64; ++i) a = fmaf(hi2[i], M3[i*FD + t], a);
        out1[r*FD + t] = a + feat[r*FD + t];
    } else if (t < 224) {
        const int o = t - 128;
        const int w = o / 3, c = o - 3*(o/3);
        float a = 0.f;
        #pragma unroll
        for (int v = 0; v < 32; ++v)
            a = fmaf(vecl[v*3 + c], Wmix[v*32 + w], a);
        out0[r*96 + o] = a + pos[r*96 + o];
    }
}

extern "C" void kernel_launch(void* const* d_in, const int* in_sizes, int n_in,
                              void* d_out, int out_size, void* d_ws, size_t ws_size,
                              hipStream_t stream)
{
    const float* pos  = (const float*)d_in[0];
    const float* feat = (const float*)d_in[1];
    const float* We1  = (const float*)d_in[2];
    const float* be1  = (const float*)d_in[3];
    const float* We2  = (const float*)d_in[4];
    const float* be2  = (const float*)d_in[5];
    const float* Wq   = (const float*)d_in[6];
    const float* Wk   = (const float*)d_in[7];
    const float* Wv   = (const float*)d_in[8];
    const float* Wvec = (const float*)d_in[9];
    const float* Wmix = (const float*)d_in[10];
    const float* M1   = (const float*)d_in[11];
    const float* bm1  = (const float*)d_in[12];
    const float* M2   = (const float*)d_in[13];
    const float* bm2  = (const float*)d_in[14];
    const float* M3   = (const float*)d_in[15];
    const float* bm3  = (const float*)d_in[16];

    float* ws = (float*)d_ws;
    float* A   = ws;                  // [256][64]
    float* Bf  = ws + 16384;          // [256][64]
    float* FV  = ws + 32768;          // [256][128]
    float* KQ  = ws + 65536;          // [256][512]
    float* lgg = ws + 196608;         // [256][256][8] f32
    u16*   cfg = (u16*)(ws + 720896); // [256][256][32] bf16
    if (ws_size < (size_t)720896*4 + (size_t)256*256*32*2) return;

    float* out0 = (float*)d_out;      // [256][32][3]
    float* out1 = out0 + NN*VC*3;     // [256][128]

    hipLaunchKernelGGL(k1_pre, dim3(256), dim3(256), 0, stream,
                       feat, We1, be1, Wq, Wk, Wv, A, Bf, FV, KQ);
    hipLaunchKernelGGL(k2_edge, dim3(512), dim3(256), 0, stream,
                       pos, We1, We2, be2, A, Bf, KQ, Wvec, lgg, cfg);
    hipLaunchKernelGGL(k3_recv, dim3(256), dim3(256), 0, stream,
                       pos, feat, lgg, cfg, FV, Wmix,
                       M1, bm1, M2, bm2, M3, bm3, out0, out1);
}

// Round 3
// 76.131 us; speedup vs baseline: 1.7131x; 1.4115x over previous
//
#include <hip/hip_runtime.h>
#include <hip/hip_bf16.h>

#define NN 256
#define VC 32
#define FD 128

typedef unsigned int uint32;
typedef unsigned short u16;
typedef __attribute__((ext_vector_type(8))) short bf16x8;
typedef __attribute__((ext_vector_type(4))) float f32x4;

__device__ __forceinline__ float selu_f(float x) {
    const float lam = 1.0507009873554805f;
    const float la  = 1.7580993408473766f;
    return x > 0.f ? lam * x : la * (__expf(x) - 1.f);
}

__device__ __forceinline__ u16 f32_to_bf16_rne(float f) {
    uint32 u = __float_as_uint(f);
    uint32 r = (u + 0x7fffu + ((u >> 16) & 1u)) >> 16;
    return (u16)r;
}

__device__ __forceinline__ float bf16_to_f32(u16 h) {
    return __uint_as_float(((uint32)h) << 16);
}

// ---------------------------------------------------------------- K1: node precompute + weight repack
__global__ __launch_bounds__(256) void k1_pre(
    const float* __restrict__ feat, const float* __restrict__ We1,
    const float* __restrict__ be1, const float* __restrict__ Wq,
    const float* __restrict__ Wk, const float* __restrict__ Wv,
    const float* __restrict__ Wvec, const float* __restrict__ We2,
    const float* __restrict__ pos,
    float* __restrict__ A, float* __restrict__ Bf, u16* __restrict__ kqb,
    u16* __restrict__ w1b, u16* __restrict__ we2b, u16* __restrict__ wvb,
    u16* __restrict__ fvtH, u16* __restrict__ fvtL,
    u16* __restrict__ ptH, u16* __restrict__ ptL,
    float* __restrict__ lgg2, u16* __restrict__ cfg2)
{
    __shared__ float fl[FD];
    __shared__ float ql[FD];
    const int n = blockIdx.x;
    const int t = threadIdx.x;
    if (t < FD) fl[t] = feat[n*FD + t];
    __syncthreads();
    if (t < 64) {
        float a = 0.f;
        for (int i = 0; i < FD; ++i) a = fmaf(fl[i], We1[i*64 + t], a);
        A[n*64 + t] = a;
    } else if (t < 128) {
        const int j = t - 64;
        float a = be1[j];
        for (int i = 0; i < FD; ++i) a = fmaf(fl[i], We1[(FD+i)*64 + j], a);
        Bf[n*64 + j] = a;
    } else {
        const int j = t - 128;
        float a = 0.f;
        for (int i = 0; i < FD; ++i) a = fmaf(fl[i], Wq[i*FD + j], a);
        ql[j] = a * 0.25f;   // fold 1/sqrt(DH)
    }
    if (t < FD) {
        float a = 0.f;
        for (int i = 0; i < FD; ++i) a = fmaf(fl[i], Wv[i*FD + t], a);
        const u16 hi = f32_to_bf16_rne(a);
        const u16 lo = f32_to_bf16_rne(a - bf16_to_f32(hi));
        fvtH[t*256 + n] = hi;
        fvtL[t*256 + n] = lo;
    }
    if (t < 128) {   // posT [32v][4c][256s] hi/lo, col3 = 1.0
        const int v = t >> 2, c = t & 3;
        const float val = (c < 3) ? pos[(n*VC + v)*3 + c] : 1.0f;
        const u16 hi = f32_to_bf16_rne(val);
        const u16 lo = f32_to_bf16_rne(val - bf16_to_f32(hi));
        ptH[(v*4+c)*256 + n] = hi;
        ptL[(v*4+c)*256 + n] = lo;
    }
    // diagonal init (self-edge excluded)
    if (t < 8)  lgg2[n*2048 + t*256 + n] = -1e30f;
    if (t < 32) cfg2[n*8192 + t*256 + n] = 0;
    __syncthreads();
    for (int o = t; o < 512; o += 256) {   // kqb[n][h][j]
        const int h = o >> 6, j = o & 63;
        float a = 0.f;
        #pragma unroll
        for (int d = 0; d < 16; ++d)
            a = fmaf(Wk[j*FD + h*16 + d], ql[h*16 + d], a);
        kqb[n*512 + o] = f32_to_bf16_rne(a);
    }
    if (n == 0) {   // weight repacks (bf16, transposed to frag-friendly layouts)
        for (int o = t; o < 16384; o += 256) {
            const int c = o >> 8, k = o & 255;
            w1b[o] = f32_to_bf16_rne(We1[(256 + k)*64 + c]);
        }
        for (int o = t; o < 4096; o += 256) {
            const int c = o >> 6, k = o & 63;
            we2b[o] = f32_to_bf16_rne(We2[k*64 + c]);
        }
        for (int o = t; o < 2048; o += 256) {
            const int v = o >> 6, k = o & 63;
            wvb[o] = f32_to_bf16_rne(Wvec[k*32 + v]);
        }
    }
}

// ---------------------------------------------------------------- K2: edge pipeline (MFMA)
__global__ __launch_bounds__(256) void k2_edge(
    const float* __restrict__ pos, const float* __restrict__ be2,
    const float* __restrict__ Ag, const float* __restrict__ Bfg,
    const u16* __restrict__ w1b, const u16* __restrict__ we2b,
    const u16* __restrict__ wvb, const u16* __restrict__ kqb,
    float* __restrict__ lgg2, u16* __restrict__ cfg2)
{
    __shared__ u16 rad[8192];       // [32e][32v][8b] bf16, xor-swizzled (16KB)
    __shared__ u16 h1b[32*64];
    __shared__ u16 h2b[32*64];
    __shared__ float invl[32*33];

    const int t = threadIdx.x;
    const int wave = t >> 6, l = t & 63;
    const int li = l & 15, q = l >> 4;
    const int mh = wave >> 1, eh = wave & 1;
    const int r = blockIdx.x >> 1, tpart = blockIdx.x & 1;
    const int e = eh*16 + li;
    const int swz16 = (e & 7) << 3;   // u16-index xor for h1b/h2b

    // ---- weight fragments (single 16B loads)
    bf16x8 w1A[2][8];
    #pragma unroll
    for (int mt = 0; mt < 2; ++mt) {
        const int c = mh*32 + mt*16 + li;
        #pragma unroll
        for (int kb = 0; kb < 8; ++kb)
            w1A[mt][kb] = *(const bf16x8*)(w1b + c*256 + kb*32 + q*8);
    }
    bf16x8 we2A[2][2];
    #pragma unroll
    for (int mt = 0; mt < 2; ++mt) {
        const int c2 = mh*32 + mt*16 + li;
        #pragma unroll
        for (int kb = 0; kb < 2; ++kb)
            we2A[mt][kb] = *(const bf16x8*)(we2b + c2*64 + kb*32 + q*8);
    }
    bf16x8 wvA[2];
    {
        const int v = mh*16 + li;
        #pragma unroll
        for (int kb = 0; kb < 2; ++kb)
            wvA[kb] = *(const bf16x8*)(wvb + v*64 + kb*32 + q*8);
    }
    bf16x8 kqA[2];
    if (li < 8) {
        #pragma unroll
        for (int kb = 0; kb < 2; ++kb)
            kqA[kb] = *(const bf16x8*)(kqb + r*512 + li*64 + kb*32 + q*8);
    } else {
        #pragma unroll
        for (int kb = 0; kb < 2; ++kb)
            #pragma unroll
            for (int j = 0; j < 8; ++j) kqA[kb][j] = 0;
    }
    float bfreg[2][4], be2reg[2][4];
    #pragma unroll
    for (int mt = 0; mt < 2; ++mt)
        #pragma unroll
        for (int rg = 0; rg < 4; ++rg) {
            const int c = mh*32 + mt*16 + q*4 + rg;
            bfreg[mt][rg] = Bfg[r*64 + c];
            be2reg[mt][rg] = be2[c];
        }

    for (int it = 0; it < 4; ++it) {
        const int s0 = (tpart*4 + it) * 32;
        const int sp = s0 + e;
        int s = sp + (sp >= r ? 1 : 0); if (s > 255) s = 255;
        __syncthreads();    // protect LDS reuse from previous tile

        // prefetch per-edge bias rows (latency overlaps P0)
        float As[2][4];
        #pragma unroll
        for (int mt = 0; mt < 2; ++mt)
            #pragma unroll
            for (int rg = 0; rg < 4; ++rg)
                As[mt][rg] = Ag[s*64 + mh*32 + mt*16 + q*4 + rg];

        // ---- P0: radial basis -> swizzled LDS (each thread 4 (e,v) pairs, no redundancy)
        {
            const int ep = t & 31, vg = t >> 5;
            const int spp = s0 + ep;
            int sv = spp + (spp >= r ? 1 : 0); if (sv > 255) sv = 255;
            #pragma unroll
            for (int kk = 0; kk < 4; ++kk) {
                const int v = vg*4 + kk;
                const float* ps = pos + (sv*VC + v)*3;
                const float* pr = pos + (r*VC + v)*3;
                const float dx = ps[0]-pr[0], dy = ps[1]-pr[1], dz = ps[2]-pr[2];
                const float d2 = fmaf(dx,dx,fmaf(dy,dy,dz*dz)) + 1e-18f;
                const float len = sqrtf(d2);
                invl[ep*33 + v] = rsqrtf(d2);
                const float x = fmaxf(len, 1e-6f);
                const float tt2 = 2.f - 0.4f*len;
                const float env = tt2 > 0.f ? 1.9784655248401538f * __expf(-1.f/tt2) : 0.f;
                const float coefc = 0.6324555320336759f * env / x;
                float s_cur, c1;
                __sincosf(0.6283185307179586f * x, &s_cur, &c1);
                const float c2x = 2.f * c1;
                float s_prev = 0.f;
                union { uint4 u4; u16 us[8]; } pk;
                #pragma unroll
                for (int b = 0; b < 8; ++b) {
                    pk.us[b] = f32_to_bf16_rne(coefc * s_cur);
                    const float s_next = fmaf(c2x, s_cur, -s_prev);
                    s_prev = s_cur; s_cur = s_next;
                }
                *(uint4*)((char*)rad + ((ep*512 + v*16) ^ ((ep & 15) << 4))) = pk.u4;
            }
        }
        __syncthreads();    // rad/invl ready

        // ---- GEMM1: h1[c][e] = radial @ We1_rad (+A[s]+Bf[r]) -> selu -> LDS bf16
        f32x4 d1[2] = {{0.f,0.f,0.f,0.f},{0.f,0.f,0.f,0.f}};
        #pragma unroll
        for (int kb = 0; kb < 8; ++kb) {
            const bf16x8 rf = *(const bf16x8*)((const char*)rad +
                                ((e*512 + (kb*4+q)*16) ^ ((e & 15) << 4)));
            d1[0] = __builtin_amdgcn_mfma_f32_16x16x32_bf16(w1A[0][kb], rf, d1[0], 0, 0, 0);
            d1[1] = __builtin_amdgcn_mfma_f32_16x16x32_bf16(w1A[1][kb], rf, d1[1], 0, 0, 0);
        }
        #pragma unroll
        for (int mt = 0; mt < 2; ++mt) {
            const int c0 = mh*32 + mt*16 + q*4;
            const u16 p0 = f32_to_bf16_rne(selu_f(d1[mt][0] + As[mt][0] + bfreg[mt][0]));
            const u16 p1 = f32_to_bf16_rne(selu_f(d1[mt][1] + As[mt][1] + bfreg[mt][1]));
            const u16 p2 = f32_to_bf16_rne(selu_f(d1[mt][2] + As[mt][2] + bfreg[mt][2]));
            const u16 p3 = f32_to_bf16_rne(selu_f(d1[mt][3] + As[mt][3] + bfreg[mt][3]));
            *(uint32*)&h1b[e*64 + ((c0)     ^ swz16)] = (uint32)p0 | ((uint32)p1 << 16);
            *(uint32*)&h1b[e*64 + ((c0 + 2) ^ swz16)] = (uint32)p2 | ((uint32)p3 << 16);
        }
        __syncthreads();

        // ---- GEMM2: h2 = selu(h1 @ We2 + be2)
        f32x4 d2[2] = {{0.f,0.f,0.f,0.f},{0.f,0.f,0.f,0.f}};
        #pragma unroll
        for (int kb = 0; kb < 2; ++kb) {
            const bf16x8 hb = *(const bf16x8*)&h1b[e*64 + ((kb*32 + q*8) ^ swz16)];
            d2[0] = __builtin_amdgcn_mfma_f32_16x16x32_bf16(we2A[0][kb], hb, d2[0], 0, 0, 0);
            d2[1] = __builtin_amdgcn_mfma_f32_16x16x32_bf16(we2A[1][kb], hb, d2[1], 0, 0, 0);
        }
        #pragma unroll
        for (int mt = 0; mt < 2; ++mt) {
            const int c0 = mh*32 + mt*16 + q*4;
            const u16 p0 = f32_to_bf16_rne(selu_f(d2[mt][0] + be2reg[mt][0]));
            const u16 p1 = f32_to_bf16_rne(selu_f(d2[mt][1] + be2reg[mt][1]));
            const u16 p2 = f32_to_bf16_rne(selu_f(d2[mt][2] + be2reg[mt][2]));
            const u16 p3 = f32_to_bf16_rne(selu_f(d2[mt][3] + be2reg[mt][3]));
            *(uint32*)&h2b[e*64 + ((c0)     ^ swz16)] = (uint32)p0 | ((uint32)p1 << 16);
            *(uint32*)&h2b[e*64 + ((c0 + 2) ^ swz16)] = (uint32)p2 | ((uint32)p3 << 16);
        }
        __syncthreads();

        // ---- GEMM3 (coeff) + logit MFMA
        f32x4 d3 = {0.f,0.f,0.f,0.f};
        f32x4 dl = {0.f,0.f,0.f,0.f};
        #pragma unroll
        for (int kb = 0; kb < 2; ++kb) {
            const bf16x8 hb = *(const bf16x8*)&h2b[e*64 + ((kb*32 + q*8) ^ swz16)];
            d3 = __builtin_amdgcn_mfma_f32_16x16x32_bf16(wvA[kb], hb, d3, 0, 0, 0);
            if (mh == 0)
                dl = __builtin_amdgcn_mfma_f32_16x16x32_bf16(kqA[kb], hb, dl, 0, 0, 0);
        }
        if (sp < 255) {
            // cfg2[r][v][s] = coeff * sqrt3 / len   (node-space)
            #pragma unroll
            for (int rg = 0; rg < 4; ++rg) {
                const int v = mh*16 + q*4 + rg;
                cfg2[(size_t)r*8192 + v*256 + s] =
                    f32_to_bf16_rne(d3[rg] * 1.7320508075688772f * invl[e*33 + v]);
            }
            // lgg2[r][h][s]
            if (mh == 0 && q < 2) {
                #pragma unroll
                for (int rg = 0; rg < 4; ++rg)
                    lgg2[(size_t)r*2048 + (q*4+rg)*256 + s] = dl[rg];
            }
        }
    }
}

// ---------------------------------------------------------------- K3a: softmax stats per (r,h)
__global__ __launch_bounds__(256) void k3a_stats(
    const float* __restrict__ lgg2, float* __restrict__ stats)
{
    const int r = blockIdx.x, t = threadIdx.x;
    const float* p = lgg2 + (size_t)r*2048 + t*8;
    const float4 a = *(const float4*)p;
    const float4 b = *(const float4*)(p + 4);
    float m = fmaxf(fmaxf(fmaxf(a.x,a.y), fmaxf(a.z,a.w)),
                    fmaxf(fmaxf(b.x,b.y), fmaxf(b.z,b.w)));
    m = fmaxf(m, __shfl_xor(m, 16));
    m = fmaxf(m, __shfl_xor(m, 8));
    m = fmaxf(m, __shfl_xor(m, 4));
    m = fmaxf(m, __shfl_xor(m, 2));
    m = fmaxf(m, __shfl_xor(m, 1));
    float ssum = __expf(a.x-m)+__expf(a.y-m)+__expf(a.z-m)+__expf(a.w-m)
               + __expf(b.x-m)+__expf(b.y-m)+__expf(b.z-m)+__expf(b.w-m);
    ssum += __shfl_xor(ssum, 16);
    ssum += __shfl_xor(ssum, 8);
    ssum += __shfl_xor(ssum, 4);
    ssum += __shfl_xor(ssum, 2);
    ssum += __shfl_xor(ssum, 1);
    if ((t & 31) == 0) {
        const int h = t >> 5;
        stats[r*16 + h*2]     = m;
        stats[r*16 + h*2 + 1] = 1.f / (ssum + 1e-12f);
    }
}

// ---------------------------------------------------------------- K3b: MFMA aggregations
// blocks 0..127: inv (h = b>>4, r-tile = b&15). blocks 128..255: vec (v = (b-128)>>2, r-chunk).
__global__ __launch_bounds__(64) void k3b_agg(
    const float* __restrict__ lgg2, const u16* __restrict__ cfg2,
    const float* __restrict__ stats,
    const u16* __restrict__ fvtH, const u16* __restrict__ fvtL,
    const u16* __restrict__ ptH, const u16* __restrict__ ptL,
    float* __restrict__ inv, float* __restrict__ vec4)
{
    const int l = threadIdx.x, li = l & 15, q = l >> 4;
    const int b = blockIdx.x;
    if (b < 128) {
        const int h = b >> 4, r0 = (b & 15) * 16;
        bf16x8 fH[8], fL[8];
        #pragma unroll
        for (int kb = 0; kb < 8; ++kb) {
            fH[kb] = *(const bf16x8*)(fvtH + (h*16+li)*256 + kb*32 + q*8);
            fL[kb] = *(const bf16x8*)(fvtL + (h*16+li)*256 + kb*32 + q*8);
        }
        const float m = stats[(r0+li)*16 + h*2];
        const float* lgr = lgg2 + (size_t)(r0+li)*2048 + h*256;
        f32x4 C = {0.f,0.f,0.f,0.f};
        #pragma unroll
        for (int kb = 0; kb < 8; ++kb) {
            const float4 g0 = *(const float4*)(lgr + kb*32 + q*8);
            const float4 g1 = *(const float4*)(lgr + kb*32 + q*8 + 4);
            bf16x8 a;
            a[0] = (short)f32_to_bf16_rne(__expf(g0.x - m));
            a[1] = (short)f32_to_bf16_rne(__expf(g0.y - m));
            a[2] = (short)f32_to_bf16_rne(__expf(g0.z - m));
            a[3] = (short)f32_to_bf16_rne(__expf(g0.w - m));
            a[4] = (short)f32_to_bf16_rne(__expf(g1.x - m));
            a[5] = (short)f32_to_bf16_rne(__expf(g1.y - m));
            a[6] = (short)f32_to_bf16_rne(__expf(g1.z - m));
            a[7] = (short)f32_to_bf16_rne(__expf(g1.w - m));
            C = __builtin_amdgcn_mfma_f32_16x16x32_bf16(a, fH[kb], C, 0, 0, 0);
            C = __builtin_amdgcn_mfma_f32_16x16x32_bf16(a, fL[kb], C, 0, 0, 0);
        }
        #pragma unroll
        for (int rg = 0; rg < 4; ++rg) {
            const int rr = r0 + q*4 + rg;
            inv[rr*128 + h*16 + li] = C[rg] * stats[rr*16 + h*2 + 1];
        }
    } else {
        const int b2 = b - 128, v = b2 >> 2, rc = b2 & 3;
        const int h = v >> 2;
        bf16x8 pH[8], pL[8];
        #pragma unroll
        for (int kb = 0; kb < 8; ++kb) {
            if (li < 4) {
                pH[kb] = *(const bf16x8*)(ptH + (v*4+li)*256 + kb*32 + q*8);
                pL[kb] = *(const bf16x8*)(ptL + (v*4+li)*256 + kb*32 + q*8);
            } else {
                #pragma unroll
                for (int j = 0; j < 8; ++j) { pH[kb][j] = 0; pL[kb][j] = 0; }
            }
        }
        #pragma unroll
        for (int mt = 0; mt < 4; ++mt) {
            const int r0 = rc*64 + mt*16;
            const float m = stats[(r0+li)*16 + h*2];
            const float* lgr = lgg2 + (size_t)(r0+li)*2048 + h*256;
            const u16* cfr = cfg2 + (size_t)(r0+li)*8192 + v*256;
            f32x4 C = {0.f,0.f,0.f,0.f};
            #pragma unroll
            for (int kb = 0; kb < 8; ++kb) {
                const float4 g0 = *(const float4*)(lgr + kb*32 + q*8);
                const float4 g1 = *(const float4*)(lgr + kb*32 + q*8 + 4);
                const bf16x8 cf8 = *(const bf16x8*)(cfr + kb*32 + q*8);
                bf16x8 a;
                a[0] = (short)f32_to_bf16_rne(__expf(g0.x - m) * bf16_to_f32((u16)cf8[0]));
                a[1] = (short)f32_to_bf16_rne(__expf(g0.y - m) * bf16_to_f32((u16)cf8[1]));
                a[2] = (short)f32_to_bf16_rne(__expf(g0.z - m) * bf16_to_f32((u16)cf8[2]));
                a[3] = (short)f32_to_bf16_rne(__expf(g0.w - m) * bf16_to_f32((u16)cf8[3]));
                a[4] = (short)f32_to_bf16_rne(__expf(g1.x - m) * bf16_to_f32((u16)cf8[4]));
                a[5] = (short)f32_to_bf16_rne(__expf(g1.y - m) * bf16_to_f32((u16)cf8[5]));
                a[6] = (short)f32_to_bf16_rne(__expf(g1.z - m) * bf16_to_f32((u16)cf8[6]));
                a[7] = (short)f32_to_bf16_rne(__expf(g1.w - m) * bf16_to_f32((u16)cf8[7]));
                C = __builtin_amdgcn_mfma_f32_16x16x32_bf16(a, pH[kb], C, 0, 0, 0);
                C = __builtin_amdgcn_mfma_f32_16x16x32_bf16(a, pL[kb], C, 0, 0, 0);
            }
            if (li < 4) {
                #pragma unroll
                for (int rg = 0; rg < 4; ++rg) {
                    const int rr = r0 + q*4 + rg;
                    vec4[rr*128 + v*4 + li] = C[rg] * stats[rr*16 + h*2 + 1];
                }
            }
        }
    }
}

// ---------------------------------------------------------------- K3c: node MLP + vec combine
__global__ __launch_bounds__(256) void k3c_out(
    const float* __restrict__ pos, const float* __restrict__ feat,
    const float* __restrict__ inv, const float* __restrict__ vec4,
    const float* __restrict__ Wmix,
    const float* __restrict__ M1, const float* __restrict__ bm1,
    const float* __restrict__ M2, const float* __restrict__ bm2,
    const float* __restrict__ M3, const float* __restrict__ bm3,
    float* __restrict__ out0, float* __restrict__ out1)
{
    __shared__ float m1s[128*64];
    __shared__ float m2s[64*64];
    __shared__ float m3s[64*128];
    __shared__ float wmixs[32*32];
    __shared__ float invas[16*128];
    __shared__ float vec4s[16*128];
    __shared__ float pos16[16*96];
    __shared__ float vecls[16*96];
    __shared__ float hi1s[16*64];
    __shared__ float hi2s[16*64];
    __shared__ float b1s[64], b2s[64], b3s[128];
    const int t = threadIdx.x;
    const int r0 = blockIdx.x * 16;
    for (int o = t; o < 8192; o += 256) m1s[o] = M1[o];
    for (int o = t; o < 4096; o += 256) m2s[o] = M2[o];
    for (int o = t; o < 8192; o += 256) m3s[o] = M3[o];
    for (int o = t; o < 1024; o += 256) wmixs[o] = Wmix[o];
    for (int o = t; o < 2048; o += 256) invas[o] = inv[r0*128 + o];
    for (int o = t; o < 2048; o += 256) vec4s[o] = vec4[r0*128 + o];
    for (int o = t; o < 1536; o += 256) pos16[o] = pos[r0*96 + o];
    if (t < 64) { b1s[t] = bm1[t]; b2s[t] = bm2[t]; }
    if (t < 128) b3s[t] = bm3[t];
    __syncthreads();
    // vecl[r'][v][c] = vec4[c] - vec4[3]*pos_r
    for (int o = t; o < 1536; o += 256) {
        const int rr = o / 96, j = o - rr*96;
        const int v = j / 3, c = j - v*3;
        vecls[o] = vec4s[rr*128 + v*4 + c] - vec4s[rr*128 + v*4 + 3] * pos16[o];
    }
    __syncthreads();
    // stage1: hi1 = selu(inva @ M1 + b1)
    {
        const int f = t & 63, rb = (t >> 6) * 4;
        float acc0 = b1s[f], acc1 = b1s[f], acc2 = b1s[f], acc3 = b1s[f];
        #pragma unroll 4
        for (int k = 0; k < 128; ++k) {
            const float w = m1s[k*64 + f];
            acc0 = fmaf(invas[(rb+0)*128 + k], w, acc0);
            acc1 = fmaf(invas[(rb+1)*128 + k], w, acc1);
            acc2 = fmaf(invas[(rb+2)*128 + k], w, acc2);
            acc3 = fmaf(invas[(rb+3)*128 + k], w, acc3);
        }
        hi1s[(rb+0)*64 + f] = selu_f(acc0);
        hi1s[(rb+1)*64 + f] = selu_f(acc1);
        hi1s[(rb+2)*64 + f] = selu_f(acc2);
        hi1s[(rb+3)*64 + f] = selu_f(acc3);
    }
    __syncthreads();
    // stage2
    {
        const int f = t & 63, rb = (t >> 6) * 4;
        float acc0 = b2s[f], acc1 = b2s[f], acc2 = b2s[f], acc3 = b2s[f];
        #pragma unroll 4
        for (int k = 0; k < 64; ++k) {
            const float w = m2s[k*64 + f];
            acc0 = fmaf(hi1s[(rb+0)*64 + k], w, acc0);
            acc1 = fmaf(hi1s[(rb+1)*64 + k], w, acc1);
            acc2 = fmaf(hi1s[(rb+2)*64 + k], w, acc2);
            acc3 = fmaf(hi1s[(rb+3)*64 + k], w, acc3);
        }
        hi2s[(rb+0)*64 + f] = selu_f(acc0);
        hi2s[(rb+1)*64 + f] = selu_f(acc1);
        hi2s[(rb+2)*64 + f] = selu_f(acc2);
        hi2s[(rb+3)*64 + f] = selu_f(acc3);
    }
    __syncthreads();
    // stage3 -> out1
    {
        const int f = t & 127, rb = (t >> 7) * 8;
        float acc[8];
        #pragma unroll
        for (int i = 0; i < 8; ++i) acc[i] = b3s[f];
        #pragma unroll 4
        for (int k = 0; k < 64; ++k) {
            const float w = m3s[k*128 + f];
            #pragma unroll
            for (int i = 0; i < 8; ++i)
                acc[i] = fmaf(hi2s[(rb+i)*64 + k], w, acc[i]);
        }
        #pragma unroll
        for (int i = 0; i < 8; ++i)
            out1[(r0+rb+i)*128 + f] = acc[i] + feat[(r0+rb+i)*128 + f];
    }
    // out0 = vecl @ Wmix + pos
    for (int o = t; o < 1536; o += 256) {
        const int rr = o / 96, j = o - rr*96;
        const int w = j / 3, c = j - w*3;
        float acc = 0.f;
        #pragma unroll
        for (int v = 0; v < 32; ++v)
            acc = fmaf(vecls[rr*96 + v*3 + c], wmixs[v*32 + w], acc);
        out0[(r0+rr)*96 + j] = acc + pos16[o];
    }
}

extern "C" void kernel_launch(void* const* d_in, const int* in_sizes, int n_in,
                              void* d_out, int out_size, void* d_ws, size_t ws_size,
                              hipStream_t stream)
{
    const float* pos  = (const float*)d_in[0];
    const float* feat = (const float*)d_in[1];
    const float* We1  = (const float*)d_in[2];
    const float* be1  = (const float*)d_in[3];
    const float* We2  = (const float*)d_in[4];
    const float* be2  = (const float*)d_in[5];
    const float* Wq   = (const float*)d_in[6];
    const float* Wk   = (const float*)d_in[7];
    const float* Wv   = (const float*)d_in[8];
    const float* Wvec = (const float*)d_in[9];
    const float* Wmix = (const float*)d_in[10];
    const float* M1   = (const float*)d_in[11];
    const float* bm1  = (const float*)d_in[12];
    const float* M2   = (const float*)d_in[13];
    const float* bm2  = (const float*)d_in[14];
    const float* M3   = (const float*)d_in[15];
    const float* bm3  = (const float*)d_in[16];

    char* ws = (char*)d_ws;
    float* A    = (float*)(ws + 0);        // [256][64]
    float* Bf   = (float*)(ws + 65536);    // [256][64]
    u16*   kqb  = (u16*)(ws + 131072);     // [256][8][64]
    u16*   w1b  = (u16*)(ws + 393216);     // [64][256]
    u16*   we2b = (u16*)(ws + 425984);     // [64][64]
    u16*   wvb  = (u16*)(ws + 434176);     // [32][64]
    u16*   fvtH = (u16*)(ws + 438272);     // [128][256]
    u16*   fvtL = (u16*)(ws + 503808);
    u16*   ptH  = (u16*)(ws + 569344);     // [32][4][256]
    u16*   ptL  = (u16*)(ws + 634880);
    float* lgg2 = (float*)(ws + 700416);   // [256][8][256]
    u16*   cfg2 = (u16*)(ws + 2797568);    // [256][32][256]
    // overlays (region of A/Bf/kqb, dead after k2)
    float* inv   = (float*)(ws + 0);       // [256][128]
    float* vec4  = (float*)(ws + 131072);  // [256][32][4]
    float* stats = (float*)(ws + 262144);  // [256][8][2]
    if (ws_size < (size_t)6991872) return;

    float* out0 = (float*)d_out;           // [256][32][3]
    float* out1 = out0 + NN*VC*3;          // [256][128]

    hipLaunchKernelGGL(k1_pre, dim3(256), dim3(256), 0, stream,
                       feat, We1, be1, Wq, Wk, Wv, Wvec, We2, pos,
                       A, Bf, kqb, w1b, we2b, wvb, fvtH, fvtL, ptH, ptL, lgg2, cfg2);
    hipLaunchKernelGGL(k2_edge, dim3(512), dim3(256), 0, stream,
                       pos, be2, A, Bf, w1b, we2b, wvb, kqb, lgg2, cfg2);
    hipLaunchKernelGGL(k3a_stats, dim3(256), dim3(256), 0, stream, lgg2, stats);
    hipLaunchKernelGGL(k3b_agg, dim3(256), dim3(64), 0, stream,
                       lgg2, cfg2, stats, fvtH, fvtL, ptH, ptL, inv, vec4);
    hipLaunchKernelGGL(k3c_out, dim3(16), dim3(256), 0, stream,
                       pos, feat, inv, vec4, Wmix,
                       M1, bm1, M2, bm2, M3, bm3, out0, out1);
}

// Round 5
// 50.236 us; speedup vs baseline: 2.5961x; 1.5155x over previous
//
#include <hip/hip_runtime.h>
#include <hip/hip_bf16.h>

#define NN 256
#define VC 32
#define FD 128

typedef unsigned int uint32;
typedef unsigned short u16;
typedef __attribute__((ext_vector_type(8))) short bf16x8;
typedef __attribute__((ext_vector_type(4))) float f32x4;

__device__ __forceinline__ float selu_f(float x) {
    const float lam = 1.0507009873554805f;
    const float la  = 1.7580993408473766f;
    return x > 0.f ? lam * x : la * (__expf(x) - 1.f);
}

__device__ __forceinline__ u16 f32_to_bf16_rne(float f) {
    uint32 u = __float_as_uint(f);
    uint32 r = (u + 0x7fffu + ((u >> 16) & 1u)) >> 16;
    return (u16)r;
}

__device__ __forceinline__ float bf16_to_f32(u16 h) {
    return __uint_as_float(((uint32)h) << 16);
}

// ---------------------------------------------------------------- K1: node precompute + weight repack
__global__ __launch_bounds__(256) void k1_pre(
    const float* __restrict__ feat, const float* __restrict__ We1,
    const float* __restrict__ be1, const float* __restrict__ Wq,
    const float* __restrict__ Wk, const float* __restrict__ Wv,
    const float* __restrict__ Wvec, const float* __restrict__ We2,
    const float* __restrict__ pos,
    float* __restrict__ A, float* __restrict__ Bf, u16* __restrict__ kqb,
    u16* __restrict__ w1b, u16* __restrict__ we2b, u16* __restrict__ wvb,
    u16* __restrict__ fvtH, u16* __restrict__ fvtL,
    u16* __restrict__ ptH, u16* __restrict__ ptL,
    float* __restrict__ lgg2, u16* __restrict__ cfg2)
{
    __shared__ float fl[FD];
    __shared__ float ql[FD];
    const int n = blockIdx.x;
    const int t = threadIdx.x;
    // ---- weight repack, spread across all blocks (1 elem/thread)
    {
        const int gid = n*256 + t;
        if (gid < 16384) {
            const int c = gid >> 8, k = gid & 255;
            w1b[gid] = f32_to_bf16_rne(We1[(256 + k)*64 + c]);
        } else if (gid < 20480) {
            const int o = gid - 16384;
            const int c = o >> 6, k = o & 63;
            we2b[o] = f32_to_bf16_rne(We2[k*64 + c]);
        } else if (gid < 22528) {
            const int o = gid - 20480;
            const int v = o >> 6, k = o & 63;
            wvb[o] = f32_to_bf16_rne(Wvec[k*32 + v]);
        }
    }
    if (t < FD) fl[t] = feat[n*FD + t];
    __syncthreads();
    if (t < 64) {
        float a = 0.f;
        for (int i = 0; i < FD; ++i) a = fmaf(fl[i], We1[i*64 + t], a);
        A[n*64 + t] = a;
    } else if (t < 128) {
        const int j = t - 64;
        float a = be1[j];
        for (int i = 0; i < FD; ++i) a = fmaf(fl[i], We1[(FD+i)*64 + j], a);
        Bf[n*64 + j] = a;
    } else {
        const int j = t - 128;
        float a = 0.f;
        for (int i = 0; i < FD; ++i) a = fmaf(fl[i], Wq[i*FD + j], a);
        ql[j] = a * 0.25f;   // fold 1/sqrt(DH)
    }
    if (t < FD) {
        float a = 0.f;
        for (int i = 0; i < FD; ++i) a = fmaf(fl[i], Wv[i*FD + t], a);
        const u16 hi = f32_to_bf16_rne(a);
        const u16 lo = f32_to_bf16_rne(a - bf16_to_f32(hi));
        fvtH[t*256 + n] = hi;
        fvtL[t*256 + n] = lo;
    }
    if (t < 128) {   // posT [32v][4c][256s] hi/lo, col3 = 1.0
        const int v = t >> 2, c = t & 3;
        const float val = (c < 3) ? pos[(n*VC + v)*3 + c] : 1.0f;
        const u16 hi = f32_to_bf16_rne(val);
        const u16 lo = f32_to_bf16_rne(val - bf16_to_f32(hi));
        ptH[(v*4+c)*256 + n] = hi;
        ptL[(v*4+c)*256 + n] = lo;
    }
    // diagonal init (self-edge excluded)
    if (t < 8)  lgg2[n*2048 + t*256 + n] = -1e30f;
    if (t < 32) cfg2[n*8192 + t*256 + n] = 0;
    __syncthreads();
    for (int o = t; o < 512; o += 256) {   // kqb[n][h][j]
        const int h = o >> 6, j = o & 63;
        float a = 0.f;
        #pragma unroll
        for (int d = 0; d < 16; ++d)
            a = fmaf(Wk[j*FD + h*16 + d], ql[h*16 + d], a);
        kqb[n*512 + o] = f32_to_bf16_rne(a);
    }
}

// ---------------------------------------------------------------- K2: edge pipeline (MFMA)
__global__ __launch_bounds__(256) void k2_edge(
    const float* __restrict__ pos, const float* __restrict__ be2,
    const float* __restrict__ Ag, const float* __restrict__ Bfg,
    const u16* __restrict__ w1b, const u16* __restrict__ we2b,
    const u16* __restrict__ wvb, const u16* __restrict__ kqb,
    float* __restrict__ lgg2, u16* __restrict__ cfg2)
{
    __shared__ u16 rad[8192];       // [32e][32v][8b] bf16, xor-swizzled (16KB)
    __shared__ u16 h1b[32*64];
    __shared__ u16 h2b[32*64];
    __shared__ float invl[32*33];

    const int t = threadIdx.x;
    const int wave = t >> 6, l = t & 63;
    const int li = l & 15, q = l >> 4;
    const int mh = wave >> 1, eh = wave & 1;
    const int r = blockIdx.x >> 1, tpart = blockIdx.x & 1;
    const int e = eh*16 + li;
    const int swz16 = (e & 7) << 3;   // u16-index xor for h1b/h2b

    // ---- weight fragments (single 16B loads)
    bf16x8 w1A[2][8];
    #pragma unroll
    for (int mt = 0; mt < 2; ++mt) {
        const int c = mh*32 + mt*16 + li;
        #pragma unroll
        for (int kb = 0; kb < 8; ++kb)
            w1A[mt][kb] = *(const bf16x8*)(w1b + c*256 + kb*32 + q*8);
    }
    bf16x8 we2A[2][2];
    #pragma unroll
    for (int mt = 0; mt < 2; ++mt) {
        const int c2 = mh*32 + mt*16 + li;
        #pragma unroll
        for (int kb = 0; kb < 2; ++kb)
            we2A[mt][kb] = *(const bf16x8*)(we2b + c2*64 + kb*32 + q*8);
    }
    bf16x8 wvA[2];
    {
        const int v = mh*16 + li;
        #pragma unroll
        for (int kb = 0; kb < 2; ++kb)
            wvA[kb] = *(const bf16x8*)(wvb + v*64 + kb*32 + q*8);
    }
    bf16x8 kqA[2];
    if (li < 8) {
        #pragma unroll
        for (int kb = 0; kb < 2; ++kb)
            kqA[kb] = *(const bf16x8*)(kqb + r*512 + li*64 + kb*32 + q*8);
    } else {
        #pragma unroll
        for (int kb = 0; kb < 2; ++kb)
            #pragma unroll
            for (int j = 0; j < 8; ++j) kqA[kb][j] = 0;
    }
    float bfreg[2][4], be2reg[2][4];
    #pragma unroll
    for (int mt = 0; mt < 2; ++mt)
        #pragma unroll
        for (int rg = 0; rg < 4; ++rg) {
            const int c = mh*32 + mt*16 + q*4 + rg;
            bfreg[mt][rg] = Bfg[r*64 + c];
            be2reg[mt][rg] = be2[c];
        }

    for (int it = 0; it < 4; ++it) {
        const int s0 = (tpart*4 + it) * 32;
        const int sp = s0 + e;
        int s = sp + (sp >= r ? 1 : 0); if (s > 255) s = 255;
        __syncthreads();    // protect LDS reuse from previous tile

        // prefetch per-edge bias rows (latency overlaps P0)
        float As[2][4];
        #pragma unroll
        for (int mt = 0; mt < 2; ++mt)
            #pragma unroll
            for (int rg = 0; rg < 4; ++rg)
                As[mt][rg] = Ag[s*64 + mh*32 + mt*16 + q*4 + rg];

        // ---- P0: radial basis -> swizzled LDS (each thread 4 (e,v) pairs, no redundancy)
        {
            const int ep = t & 31, vg = t >> 5;
            const int spp = s0 + ep;
            int sv = spp + (spp >= r ? 1 : 0); if (sv > 255) sv = 255;
            #pragma unroll
            for (int kk = 0; kk < 4; ++kk) {
                const int v = vg*4 + kk;
                const float* ps = pos + (sv*VC + v)*3;
                const float* pr = pos + (r*VC + v)*3;
                const float dx = ps[0]-pr[0], dy = ps[1]-pr[1], dz = ps[2]-pr[2];
                const float d2 = fmaf(dx,dx,fmaf(dy,dy,dz*dz)) + 1e-18f;
                const float len = sqrtf(d2);
                invl[ep*33 + v] = rsqrtf(d2);
                const float x = fmaxf(len, 1e-6f);
                const float tt2 = 2.f - 0.4f*len;
                const float env = tt2 > 0.f ? 1.9784655248401538f * __expf(-1.f/tt2) : 0.f;
                const float coefc = 0.6324555320336759f * env / x;
                float s_cur, c1;
                __sincosf(0.6283185307179586f * x, &s_cur, &c1);
                const float c2x = 2.f * c1;
                float s_prev = 0.f;
                union { uint4 u4; u16 us[8]; } pk;
                #pragma unroll
                for (int b = 0; b < 8; ++b) {
                    pk.us[b] = f32_to_bf16_rne(coefc * s_cur);
                    const float s_next = fmaf(c2x, s_cur, -s_prev);
                    s_prev = s_cur; s_cur = s_next;
                }
                *(uint4*)((char*)rad + ((ep*512 + v*16) ^ ((ep & 15) << 4))) = pk.u4;
            }
        }
        __syncthreads();    // rad/invl ready

        // ---- GEMM1: h1[c][e] = radial @ We1_rad (+A[s]+Bf[r]) -> selu -> LDS bf16
        f32x4 d1[2] = {{0.f,0.f,0.f,0.f},{0.f,0.f,0.f,0.f}};
        #pragma unroll
        for (int kb = 0; kb < 8; ++kb) {
            const bf16x8 rf = *(const bf16x8*)((const char*)rad +
                                ((e*512 + (kb*4+q)*16) ^ ((e & 15) << 4)));
            d1[0] = __builtin_amdgcn_mfma_f32_16x16x32_bf16(w1A[0][kb], rf, d1[0], 0, 0, 0);
            d1[1] = __builtin_amdgcn_mfma_f32_16x16x32_bf16(w1A[1][kb], rf, d1[1], 0, 0, 0);
        }
        #pragma unroll
        for (int mt = 0; mt < 2; ++mt) {
            const int c0 = mh*32 + mt*16 + q*4;
            const u16 p0 = f32_to_bf16_rne(selu_f(d1[mt][0] + As[mt][0] + bfreg[mt][0]));
            const u16 p1 = f32_to_bf16_rne(selu_f(d1[mt][1] + As[mt][1] + bfreg[mt][1]));
            const u16 p2 = f32_to_bf16_rne(selu_f(d1[mt][2] + As[mt][2] + bfreg[mt][2]));
            const u16 p3 = f32_to_bf16_rne(selu_f(d1[mt][3] + As[mt][3] + bfreg[mt][3]));
            *(uint32*)&h1b[e*64 + ((c0)     ^ swz16)] = (uint32)p0 | ((uint32)p1 << 16);
            *(uint32*)&h1b[e*64 + ((c0 + 2) ^ swz16)] = (uint32)p2 | ((uint32)p3 << 16);
        }
        __syncthreads();

        // ---- GEMM2: h2 = selu(h1 @ We2 + be2)
        f32x4 d2[2] = {{0.f,0.f,0.f,0.f},{0.f,0.f,0.f,0.f}};
        #pragma unroll
        for (int kb = 0; kb < 2; ++kb) {
            const bf16x8 hb = *(const bf16x8*)&h1b[e*64 + ((kb*32 + q*8) ^ swz16)];
            d2[0] = __builtin_amdgcn_mfma_f32_16x16x32_bf16(we2A[0][kb], hb, d2[0], 0, 0, 0);
            d2[1] = __builtin_amdgcn_mfma_f32_16x16x32_bf16(we2A[1][kb], hb, d2[1], 0, 0, 0);
        }
        #pragma unroll
        for (int mt = 0; mt < 2; ++mt) {
            const int c0 = mh*32 + mt*16 + q*4;
            const u16 p0 = f32_to_bf16_rne(selu_f(d2[mt][0] + be2reg[mt][0]));
            const u16 p1 = f32_to_bf16_rne(selu_f(d2[mt][1] + be2reg[mt][1]));
            const u16 p2 = f32_to_bf16_rne(selu_f(d2[mt][2] + be2reg[mt][2]));
            const u16 p3 = f32_to_bf16_rne(selu_f(d2[mt][3] + be2reg[mt][3]));
            *(uint32*)&h2b[e*64 + ((c0)     ^ swz16)] = (uint32)p0 | ((uint32)p1 << 16);
            *(uint32*)&h2b[e*64 + ((c0 + 2) ^ swz16)] = (uint32)p2 | ((uint32)p3 << 16);
        }
        __syncthreads();

        // ---- GEMM3 (coeff) + logit MFMA
        f32x4 d3 = {0.f,0.f,0.f,0.f};
        f32x4 dl = {0.f,0.f,0.f,0.f};
        #pragma unroll
        for (int kb = 0; kb < 2; ++kb) {
            const bf16x8 hb = *(const bf16x8*)&h2b[e*64 + ((kb*32 + q*8) ^ swz16)];
            d3 = __builtin_amdgcn_mfma_f32_16x16x32_bf16(wvA[kb], hb, d3, 0, 0, 0);
            if (mh == 0)
                dl = __builtin_amdgcn_mfma_f32_16x16x32_bf16(kqA[kb], hb, dl, 0, 0, 0);
        }
        if (sp < 255) {
            // cfg2[r][v][s] = coeff * sqrt3 / len   (node-space)
            #pragma unroll
            for (int rg = 0; rg < 4; ++rg) {
                const int v = mh*16 + q*4 + rg;
                cfg2[(size_t)r*8192 + v*256 + s] =
                    f32_to_bf16_rne(d3[rg] * 1.7320508075688772f * invl[e*33 + v]);
            }
            // lgg2[r][h][s]
            if (mh == 0 && q < 2) {
                #pragma unroll
                for (int rg = 0; rg < 4; ++rg)
                    lgg2[(size_t)r*2048 + (q*4+rg)*256 + s] = dl[rg];
            }
        }
    }
}

// ---------------------------------------------------------------- K3b: MFMA aggregations + fused softmax stats
// blocks 0..127: inv (h = b>>4, rtile = b&15). blocks 128..639: vec (v = (b-128)>>4, rtile = (b-128)&15).
__global__ __launch_bounds__(64) void k3b_agg(
    const float* __restrict__ lgg2, const u16* __restrict__ cfg2,
    const u16* __restrict__ fvtH, const u16* __restrict__ fvtL,
    const u16* __restrict__ ptH, const u16* __restrict__ ptL,
    float* __restrict__ inv, float* __restrict__ vec4)
{
    const int l = threadIdx.x, li = l & 15, q = l >> 4;
    const int b = blockIdx.x;
    if (b < 128) {
        const int h = b >> 4, r0 = (b & 15) * 16;
        bf16x8 fH[8], fL[8];
        #pragma unroll
        for (int kb = 0; kb < 8; ++kb) {
            fH[kb] = *(const bf16x8*)(fvtH + (h*16+li)*256 + kb*32 + q*8);
            fL[kb] = *(const bf16x8*)(fvtL + (h*16+li)*256 + kb*32 + q*8);
        }
        const float* lgr = lgg2 + (size_t)(r0+li)*2048 + h*256;
        // pass 1: row max (row = r0+li), reduce over q-lanes
        float mx = -3.0e38f;
        #pragma unroll
        for (int kb = 0; kb < 8; ++kb) {
            const float4 g0 = *(const float4*)(lgr + kb*32 + q*8);
            const float4 g1 = *(const float4*)(lgr + kb*32 + q*8 + 4);
            mx = fmaxf(mx, fmaxf(fmaxf(g0.x,g0.y), fmaxf(g0.z,g0.w)));
            mx = fmaxf(mx, fmaxf(fmaxf(g1.x,g1.y), fmaxf(g1.z,g1.w)));
        }
        mx = fmaxf(mx, __shfl_xor(mx, 16));
        mx = fmaxf(mx, __shfl_xor(mx, 32));
        // pass 2: exp + MFMA + denom
        float sm = 0.f;
        f32x4 C = {0.f,0.f,0.f,0.f};
        #pragma unroll
        for (int kb = 0; kb < 8; ++kb) {
            const float4 g0 = *(const float4*)(lgr + kb*32 + q*8);
            const float4 g1 = *(const float4*)(lgr + kb*32 + q*8 + 4);
            float ev[8];
            ev[0]=__expf(g0.x-mx); ev[1]=__expf(g0.y-mx); ev[2]=__expf(g0.z-mx); ev[3]=__expf(g0.w-mx);
            ev[4]=__expf(g1.x-mx); ev[5]=__expf(g1.y-mx); ev[6]=__expf(g1.z-mx); ev[7]=__expf(g1.w-mx);
            bf16x8 a;
            #pragma unroll
            for (int j = 0; j < 8; ++j) { sm += ev[j]; a[j] = (short)f32_to_bf16_rne(ev[j]); }
            C = __builtin_amdgcn_mfma_f32_16x16x32_bf16(a, fH[kb], C, 0, 0, 0);
            C = __builtin_amdgcn_mfma_f32_16x16x32_bf16(a, fL[kb], C, 0, 0, 0);
        }
        sm += __shfl_xor(sm, 16);
        sm += __shfl_xor(sm, 32);
        #pragma unroll
        for (int rg = 0; rg < 4; ++rg) {
            const float d = __shfl(sm, q*4 + rg);
            inv[(r0 + q*4 + rg)*128 + h*16 + li] = C[rg] / (d + 1e-12f);
        }
    } else {
        const int b2 = b - 128, v = b2 >> 4, r0 = (b2 & 15) * 16;
        const int h = v >> 2;
        bf16x8 pH[8], pL[8];
        #pragma unroll
        for (int kb = 0; kb < 8; ++kb) {
            if (li < 4) {
                pH[kb] = *(const bf16x8*)(ptH + (v*4+li)*256 + kb*32 + q*8);
                pL[kb] = *(const bf16x8*)(ptL + (v*4+li)*256 + kb*32 + q*8);
            } else {
                #pragma unroll
                for (int j = 0; j < 8; ++j) { pH[kb][j] = 0; pL[kb][j] = 0; }
            }
        }
        const float* lgr = lgg2 + (size_t)(r0+li)*2048 + h*256;
        const u16*  cfr = cfg2 + (size_t)(r0+li)*8192 + v*256;
        float mx = -3.0e38f;
        #pragma unroll
        for (int kb = 0; kb < 8; ++kb) {
            const float4 g0 = *(const float4*)(lgr + kb*32 + q*8);
            const float4 g1 = *(const float4*)(lgr + kb*32 + q*8 + 4);
            mx = fmaxf(mx, fmaxf(fmaxf(g0.x,g0.y), fmaxf(g0.z,g0.w)));
            mx = fmaxf(mx, fmaxf(fmaxf(g1.x,g1.y), fmaxf(g1.z,g1.w)));
        }
        mx = fmaxf(mx, __shfl_xor(mx, 16));
        mx = fmaxf(mx, __shfl_xor(mx, 32));
        float sm = 0.f;
        f32x4 C = {0.f,0.f,0.f,0.f};
        #pragma unroll
        for (int kb = 0; kb < 8; ++kb) {
            const float4 g0 = *(const float4*)(lgr + kb*32 + q*8);
            const float4 g1 = *(const float4*)(lgr + kb*32 + q*8 + 4);
            const bf16x8 cf8 = *(const bf16x8*)(cfr + kb*32 + q*8);
            float ev[8];
            ev[0]=__expf(g0.x-mx); ev[1]=__expf(g0.y-mx); ev[2]=__expf(g0.z-mx); ev[3]=__expf(g0.w-mx);
            ev[4]=__expf(g1.x-mx); ev[5]=__expf(g1.y-mx); ev[6]=__expf(g1.z-mx); ev[7]=__expf(g1.w-mx);
            bf16x8 a;
            #pragma unroll
            for (int j = 0; j < 8; ++j) {
                sm += ev[j];
                a[j] = (short)f32_to_bf16_rne(ev[j] * bf16_to_f32((u16)cf8[j]));
            }
            C = __builtin_amdgcn_mfma_f32_16x16x32_bf16(a, pH[kb], C, 0, 0, 0);
            C = __builtin_amdgcn_mfma_f32_16x16x32_bf16(a, pL[kb], C, 0, 0, 0);
        }
        sm += __shfl_xor(sm, 16);
        sm += __shfl_xor(sm, 32);
        #pragma unroll
        for (int rg = 0; rg < 4; ++rg) {
            const float d = __shfl(sm, q*4 + rg);
            if (li < 4)
                vec4[(r0 + q*4 + rg)*128 + v*4 + li] = C[rg] / (d + 1e-12f);
        }
    }
}

// ---------------------------------------------------------------- K3c: node MLP + vec combine (4 nodes/block)
__global__ __launch_bounds__(256) void k3c_out(
    const float* __restrict__ pos, const float* __restrict__ feat,
    const float* __restrict__ inv, const float* __restrict__ vec4,
    const float* __restrict__ Wmix,
    const float* __restrict__ M1, const float* __restrict__ bm1,
    const float* __restrict__ M2, const float* __restrict__ bm2,
    const float* __restrict__ M3, const float* __restrict__ bm3,
    float* __restrict__ out0, float* __restrict__ out1)
{
    __shared__ float m1s[128*64];
    __shared__ float m2s[64*64];
    __shared__ float m3s[64*128];
    __shared__ float wmixs[32*32];
    __shared__ float invas[4*128];
    __shared__ float vec4s[4*128];
    __shared__ float pos4[4*96];
    __shared__ float vecls[4*96];
    __shared__ float hi1s[4*64];
    __shared__ float hi2s[4*64];
    __shared__ float b1s[64], b2s[64], b3s[128];
    const int t = threadIdx.x;
    const int r0 = blockIdx.x * 4;
    for (int o = t; o < 8192; o += 256) m1s[o] = M1[o];
    for (int o = t; o < 4096; o += 256) m2s[o] = M2[o];
    for (int o = t; o < 8192; o += 256) m3s[o] = M3[o];
    for (int o = t; o < 1024; o += 256) wmixs[o] = Wmix[o];
    for (int o = t; o < 512; o += 256) invas[o] = inv[r0*128 + o];
    for (int o = t; o < 512; o += 256) vec4s[o] = vec4[r0*128 + o];
    for (int o = t; o < 384; o += 256) pos4[o] = pos[r0*96 + o];   // FIX: loop, not if(t<384)
    if (t < 64) { b1s[t] = bm1[t]; b2s[t] = bm2[t]; }
    if (t < 128) b3s[t] = bm3[t];
    __syncthreads();
    // vecl[r'][v][c] = vec4[c] - vec4[3]*pos_r
    for (int o = t; o < 384; o += 256) {                            // FIX: loop, not if(t<384)
        const int rr = o / 96, j = o - rr*96;
        const int v = j / 3, c = j - v*3;
        vecls[o] = vec4s[rr*128 + v*4 + c] - vec4s[rr*128 + v*4 + 3] * pos4[o];
    }
    __syncthreads();
    // stage1: hi1 = selu(inva @ M1 + b1)   (one output per thread: 4r x 64f)
    {
        const int f = t & 63, rr = t >> 6;
        float acc = b1s[f];
        #pragma unroll 8
        for (int k = 0; k < 128; ++k)
            acc = fmaf(invas[rr*128 + k], m1s[k*64 + f], acc);
        hi1s[rr*64 + f] = selu_f(acc);
    }
    __syncthreads();
    // stage2
    {
        const int f = t & 63, rr = t >> 6;
        float acc = b2s[f];
        #pragma unroll 8
        for (int k = 0; k < 64; ++k)
            acc = fmaf(hi1s[rr*64 + k], m2s[k*64 + f], acc);
        hi2s[rr*64 + f] = selu_f(acc);
    }
    __syncthreads();
    // stage3 -> out1   (4r x 128f = 512 outputs)
    for (int o = t; o < 512; o += 256) {
        const int f = o & 127, rr = o >> 7;
        float acc = b3s[f];
        #pragma unroll 8
        for (int k = 0; k < 64; ++k)
            acc = fmaf(hi2s[rr*64 + k], m3s[k*128 + f], acc);
        out1[(r0+rr)*128 + f] = acc + feat[(r0+rr)*128 + f];
    }
    // out0 = vecl @ Wmix + pos   (4r x 96 = 384 outputs)
    for (int o = t; o < 384; o += 256) {
        const int rr = o / 96, j = o - rr*96;
        const int w = j / 3, c = j - w*3;
        float acc = 0.f;
        #pragma unroll
        for (int v = 0; v < 32; ++v)
            acc = fmaf(vecls[rr*96 + v*3 + c], wmixs[v*32 + w], acc);
        out0[(r0+rr)*96 + j] = acc + pos4[o];
    }
}

extern "C" void kernel_launch(void* const* d_in, const int* in_sizes, int n_in,
                              void* d_out, int out_size, void* d_ws, size_t ws_size,
                              hipStream_t stream)
{
    const float* pos  = (const float*)d_in[0];
    const float* feat = (const float*)d_in[1];
    const float* We1  = (const float*)d_in[2];
    const float* be1  = (const float*)d_in[3];
    const float* We2  = (const float*)d_in[4];
    const float* be2  = (const float*)d_in[5];
    const float* Wq   = (const float*)d_in[6];
    const float* Wk   = (const float*)d_in[7];
    const float* Wv   = (const float*)d_in[8];
    const float* Wvec = (const float*)d_in[9];
    const float* Wmix = (const float*)d_in[10];
    const float* M1   = (const float*)d_in[11];
    const float* bm1  = (const float*)d_in[12];
    const float* M2   = (const float*)d_in[13];
    const float* bm2  = (const float*)d_in[14];
    const float* M3   = (const float*)d_in[15];
    const float* bm3  = (const float*)d_in[16];

    char* ws = (char*)d_ws;
    float* A    = (float*)(ws + 0);        // [256][64]
    float* Bf   = (float*)(ws + 65536);    // [256][64]
    u16*   kqb  = (u16*)(ws + 131072);     // [256][8][64]
    u16*   w1b  = (u16*)(ws + 393216);     // [64][256]
    u16*   we2b = (u16*)(ws + 425984);     // [64][64]
    u16*   wvb  = (u16*)(ws + 434176);     // [32][64]
    u16*   fvtH = (u16*)(ws + 438272);     // [128][256]
    u16*   fvtL = (u16*)(ws + 503808);
    u16*   ptH  = (u16*)(ws + 569344);     // [32][4][256]
    u16*   ptL  = (u16*)(ws + 634880);
    float* lgg2 = (float*)(ws + 700416);   // [256][8][256]
    u16*   cfg2 = (u16*)(ws + 2797568);    // [256][32][256]
    // overlays (region of A/Bf/kqb, dead after k2)
    float* inv   = (float*)(ws + 0);       // [256][128]
    float* vec4  = (float*)(ws + 131072);  // [256][32][4]
    if (ws_size < (size_t)6991872) return;

    float* out0 = (float*)d_out;           // [256][32][3]
    float* out1 = out0 + NN*VC*3;          // [256][128]

    hipLaunchKernelGGL(k1_pre, dim3(256), dim3(256), 0, stream,
                       feat, We1, be1, Wq, Wk, Wv, Wvec, We2, pos,
                       A, Bf, kqb, w1b, we2b, wvb, fvtH, fvtL, ptH, ptL, lgg2, cfg2);
    hipLaunchKernelGGL(k2_edge, dim3(512), dim3(256), 0, stream,
                       pos, be2, A, Bf, w1b, we2b, wvb, kqb, lgg2, cfg2);
    hipLaunchKernelGGL(k3b_agg, dim3(640), dim3(64), 0, stream,
                       lgg2, cfg2, fvtH, fvtL, ptH, ptL, inv, vec4);
    hipLaunchKernelGGL(k3c_out, dim3(64), dim3(256), 0, stream,
                       pos, feat, inv, vec4, Wmix,
                       M1, bm1, M2, bm2, M3, bm3, out0, out1);
}